// Round 16
// baseline (190.112 us; speedup 1.0000x reference)
//
#include <hip/hip_runtime.h>
#include <hip/hip_bf16.h>
#include <stdint.h>

#define B_ 8
#define S_ 1024
#define NV_ 768
#define D_ 512
#define DF_ 2048
#define H_ 8
#define DH_ 64
#define BS_ (B_*S_)
#define BSD_ ((size_t)B_*S_*D_)
#define QKLD 2048   // qk buffer leading dim: [q1|k1|q2|k2] x 512

typedef __bf16 bf16x8 __attribute__((ext_vector_type(8)));
typedef float f32x4 __attribute__((ext_vector_type(4)));
typedef float f32x16 __attribute__((ext_vector_type(16)));
typedef __hip_bfloat16 bf16;

__device__ __forceinline__ void async_copy16(const void* g, void* l) {
  __builtin_amdgcn_global_load_lds((const __attribute__((address_space(1))) void*)g,
                                   (__attribute__((address_space(3))) void*)l, 16, 0, 0);
}

// ---------------- GEMM swizzle (16-row fragments); NT = threads in block ----
template<int NT>
__device__ __forceinline__ void stage_tile(const bf16* __restrict__ g, int gRow0, long ldg,
                                           int gCol0, bf16* lds, int rows, int tid) {
  const int totalBytes = rows << 7;
  for (int off = tid * 16; off < totalBytes; off += NT * 16) {
    const int r = off >> 7;
    const int c = off & 127;
    const int srcByte = c ^ ((r & 7) << 4);
    const bf16* gp = g + (long)(gRow0 + r) * ldg + gCol0 + (srcByte >> 1);
    async_copy16(gp, (char*)lds + off);
  }
}
__device__ __forceinline__ bf16x8 lds_frag(const bf16* base, int row, int kElem) {
  const int byte = (row << 7) + ((kElem << 1) ^ ((row & 7) << 4));
  return *(const bf16x8*)((const char*)base + byte);
}

// ---------------- flash swizzle (32-row fragments, stride-8 read phases) -----
__device__ __forceinline__ int fswz(int row) {
  return ((((row >> 3) & 3) << 1) | (row & 1)) << 4;
}

// Fast 2^s -> bf16 fragment, Schraudolph: bits=(int)(2^23*s + bias).
// No max subtraction: |s| <= ~24 by Cauchy-Schwarz on q,k norms; valid (-126,30).
#define SCH_BIAS 1064872540.f
template<int BASE>
__device__ __forceinline__ bf16x8 pexp_frag(const f32x16& s) {
  union { unsigned u[4]; bf16x8 b; } r;
#pragma unroll
  for (int e = 0; e < 4; e++) {
    const int i0 = (int)fmaf(s[BASE + 2 * e], 8388608.f, SCH_BIAS);
    const int i1 = (int)fmaf(s[BASE + 2 * e + 1], 8388608.f, SCH_BIAS);
    r.u[e] = __builtin_amdgcn_perm((unsigned)i1, (unsigned)i0, 0x07060302u);
  }
  return r.b;
}

__device__ __forceinline__ bf16x8 ones_frag() {
  union { ushort u[8]; bf16x8 b; } r;
#pragma unroll
  for (int e = 0; e < 8; e++) r.u[e] = 0x3F80;  // bf16 1.0
  return r.b;
}

__device__ __forceinline__ f32x16 zero16() {
  f32x16 z;
#pragma unroll
  for (int i = 0; i < 16; i++) z[i] = 0.f;
  return z;
}

// ---------- merged 16-panel weight transpose+convert ----------
struct WPanel { const float* src; bf16* dst; int srcLd, dstLd; float scale; };
struct WP16 { WPanel p[16]; };
__global__ __launch_bounds__(256) void wtrans16_kernel(WP16 ws) {
  __shared__ float tile[32][33];
  const WPanel pa = ws.p[blockIdx.z];
  const int tx = threadIdx.x, ty = threadIdx.y;
  const int n0 = blockIdx.x * 32, k0 = blockIdx.y * 32;
#pragma unroll
  for (int i = 0; i < 4; i++)
    tile[ty + i * 8][tx] = pa.src[(long)(k0 + ty + i * 8) * pa.srcLd + n0 + tx];
  __syncthreads();
#pragma unroll
  for (int i = 0; i < 4; i++)
    pa.dst[(long)(n0 + ty + i * 8) * pa.dstLd + k0 + tx] =
        __float2bfloat16(tile[tx][ty + i * 8] * pa.scale);
}

// ---------- gather + fp32->bf16 ----------
__global__ __launch_bounds__(256) void gather_cvt_kernel(const float* __restrict__ x,
                                                         const int* __restrict__ idx,
                                                         const int* __restrict__ Np,
                                                         bf16* __restrict__ out) {
  const int N = *Np;
  const int row = blockIdx.x * 2 + (threadIdx.x >> 7);
  const int t = threadIdx.x & 127;
  const int b = row >> 10, s = row & 1023;
  const int src = (s < N) ? idx[b * NV_ + s] : s;
  const float4 v = *(const float4*)(x + ((long)b * S_ + src) * D_ + t * 4);
  ushort4 u;
  u.x = (ushort)__bfloat16_as_ushort(__float2bfloat16(v.x));
  u.y = (ushort)__bfloat16_as_ushort(__float2bfloat16(v.y));
  u.z = (ushort)__bfloat16_as_ushort(__float2bfloat16(v.z));
  u.w = (ushort)__bfloat16_as_ushort(__float2bfloat16(v.w));
  *(ushort4*)(out + (long)row * D_ + t * 4) = u;
}

// ---------- GEMM (R15 proven: 2-barrier + XCD swizzle + K-stagger) -----------
// K-phase stagger: block starts its K loop at phase (l & (nk-1)) and wraps —
// accumulation commutative; desyncs the stage-burst convoy across blocks.
// QKV mode: logical N=3072 (two sets of [Q|K|V]); Q/K cols -> qk[row][set*1024+c1]
// (ld 2048); V cols -> vtb (B,H,DH,S layout, key bits 2<->3 permuted).
template<int BM, int BN, int MR, int NR, int OUTF, int BIAS, int RELU, int QKV>
__global__ __launch_bounds__(BM / (MR * 16) * (BN / (NR * 16)) * 64, 4)
void gemm_bt(const bf16* __restrict__ A, long lda, long sAz,
             const bf16* __restrict__ Bt, long sBz,
             const float* __restrict__ bias,
             void* __restrict__ C, long ldc, long sCz,
             int K, bf16* __restrict__ vtbOut) {
  constexpr int WC = BN / (NR * 16);
  constexpr int WR = BM / (MR * 16);
  constexpr int NT = WR * WC * 64;
  __shared__ bf16 As[BM * 64];
  __shared__ bf16 Bs[BN * 64];
  const int tid = threadIdx.x;
  const int lane = tid & 63, wave = tid >> 6;
  const int wr = wave / WC, wc = wave % WC;
  const int g = lane >> 4, lr = lane & 15;

  // XCD-chunked swizzle (bijective; gridDim.x%8==0 for all our grids)
  const int nx = gridDim.x;
  const int ch = nx >> 3;
  const int l = blockIdx.x + nx * blockIdx.y;
  const int xcd = l & 7, i = l >> 3;
  const int bx = xcd * ch + i % ch;
  const int by = i / ch;
  const int m0 = bx * BM, n0 = by * BN;
  const int z = blockIdx.z;
  A += (long)z * sAz;
  Bt += (long)z * sBz;

  f32x4 acc[MR][NR];
#pragma unroll
  for (int m = 0; m < MR; m++)
#pragma unroll
    for (int n = 0; n < NR; n++) acc[m][n] = (f32x4){0.f, 0.f, 0.f, 0.f};

  const int nk = K >> 6;                 // power of 2 for all our shapes
  const int ph = l & (nk - 1);           // per-block K start phase
#pragma unroll 1
  for (int s = 0; s < nk; s++) {
    const int kt = ((s + ph) & (nk - 1)) << 6;
    stage_tile<NT>(A, m0, lda, kt, As, BM, tid);
    stage_tile<NT>(Bt, n0, K, kt, Bs, BN, tid);
    __syncthreads();
#pragma unroll
    for (int ks = 0; ks < 64; ks += 32) {
      const int kk = ks + g * 8;
      bf16x8 aF[MR], bF[NR];
#pragma unroll
      for (int m = 0; m < MR; m++) aF[m] = lds_frag(As, wr * (MR * 16) + m * 16 + lr, kk);
#pragma unroll
      for (int n = 0; n < NR; n++) bF[n] = lds_frag(Bs, wc * (NR * 16) + n * 16 + lr, kk);
#pragma unroll
      for (int m = 0; m < MR; m++)
#pragma unroll
        for (int n = 0; n < NR; n++)
          acc[m][n] = __builtin_amdgcn_mfma_f32_16x16x32_bf16(aF[m], bF[n], acc[m][n], 0, 0, 0);
    }
    __syncthreads();
  }

#pragma unroll
  for (int m = 0; m < MR; m++) {
#pragma unroll
    for (int n = 0; n < NR; n++) {
      const int row = m0 + wr * (MR * 16) + m * 16 + g * 4;
      const int col = n0 + wc * (NR * 16) + n * 16 + lr;
      if (QKV) {
        const int set = (col >= 1536) ? 1 : 0;
        const int c1 = col - set * 1536;
        if (c1 < 1024) {           // Q or K column -> qk buffer (block-uniform)
          bf16* cp = (bf16*)C + (long)row * QKLD + set * 1024 + c1;
#pragma unroll
          for (int r = 0; r < 4; r++) cp[(long)r * QKLD] = __float2bfloat16(acc[m][n][r]);
        } else {                   // V column -> vtb transposed + key-permuted
          const int d = c1 - 1024;                       // 0..511
          const int zz = set * 64 + ((row >> 10) << 3) + (d >> 6);
          const int s2 = row & 1023;                     // bits 0-1 zero; bits 2-3 const
          const int sp = (s2 & ~12) | ((s2 & 4) << 1) | ((s2 & 8) >> 1);
          ushort4 pk;
          pk.x = (ushort)__bfloat16_as_ushort(__float2bfloat16(acc[m][n][0]));
          pk.y = (ushort)__bfloat16_as_ushort(__float2bfloat16(acc[m][n][1]));
          pk.z = (ushort)__bfloat16_as_ushort(__float2bfloat16(acc[m][n][2]));
          pk.w = (ushort)__bfloat16_as_ushort(__float2bfloat16(acc[m][n][3]));
          *(ushort4*)(vtbOut + (((long)(zz * 64 + (d & 63))) << 10) + sp) = pk;
        }
      } else {
        const float bv = BIAS ? bias[col] : 0.f;
#pragma unroll
        for (int r = 0; r < 4; r++) {
          float v = acc[m][n][r] + bv;
          if (RELU) v = fmaxf(v, 0.f);
          if (OUTF) ((float*)C)[(long)z * sCz + (long)(row + r) * ldc + col] = v;
          else ((bf16*)C)[(long)z * sCz + (long)(row + r) * ldc + col] = __float2bfloat16(v);
        }
      }
    }
  }
}

// ---------- flash attention (R11 proven + KV-tile stagger) -------------------
// 2 q-groups double the compute window per KV tile and halve K/V traffic.
// Q fills 32KB LDS, hoisted to regs; LDS becomes 2x16KB KV rotate-buffer.
// KV-tile stagger: no online softmax -> tile sums commutative; block visits
// tiles in order (t + qt*4) & 15 so same-sbh blocks on one XCD desync their
// barrier/refill convoys (same mechanism as the R15 GEMM K-stagger win).
__global__ __launch_bounds__(256, 2) void flash_kernel(bf16* __restrict__ qk,
                                                       const bf16* __restrict__ vtb) {
  __shared__ char lds[32768];
  const int tid = threadIdx.x;
  const int lane = tid & 63, warp = tid >> 6;
  const int qlo = lane & 31, hi = lane >> 5;

  // bijective XCD swizzle: each XCD gets 64 consecutive swz ids (16 sbh units)
  const int bid = (int)blockIdx.x;
  const int swz = (bid & 7) * 64 + (bid >> 3);
  const int qt = swz & 3;                 // 4 q-tiles of 256 rows
  const int sbh = swz >> 2;               // set*64 + b*8 + h
  const int set = sbh >> 6;
  const int b = (sbh >> 3) & 7, h = sbh & 7;

  bf16* Qp = qk + (long)b * S_ * QKLD + set * 1024 + h * DH_;
  const bf16* Kp = Qp + 512;
  const bf16* Vp = vtb + (long)sbh * DH_ * S_;

  // staging geometry (tile-invariant): thread covers row r0 (+32k) per 4KB chunk
  const int r0 = tid >> 3;
  const int cbyt = (tid & 7) << 4;
  const int sb = cbyt ^ fswz(r0);         // fswz(r0+32k) == fswz(r0)
  char* const ld0 = lds + tid * 16;       // wave-linear LDS dest

  // Q: 256 rows fill all 32KB (chunk i holds rows i*32 + r0)
  {
    const bf16* qS = Qp + (long)(qt * 256 + r0) * QKLD + (sb >> 1);
#pragma unroll
    for (int i = 0; i < 8; i++) async_copy16(qS + (long)i * 32 * QKLD, ld0 + i * 4096);
  }
  __syncthreads();

  // hoist Q frags; global row R lives at byte (R<<7)|fswz(R) (since 32*128=4096)
  const int qrow = warp * 32 + qlo;
  const int qrb = (qrow << 7) | fswz(qrow);
  bf16x8 qA[4], qB[4];
#pragma unroll
  for (int d4 = 0; d4 < 4; d4++) {
    const int kc2 = d4 * 32 + hi * 16;
    qA[d4] = *(const bf16x8*)(lds + (qrb ^ kc2));
    qB[d4] = *(const bf16x8*)(lds + ((qrb + 16384) ^ kc2));
  }
  __syncthreads();   // Q consumed; whole LDS free for KV buffers

  const bf16* const kS0 = Kp + (long)r0 * QKLD + (sb >> 1);
  const bf16* const vS0 = Vp + (long)r0 * S_ + (sb >> 1);
  const int tph = qt * 4;                 // per-block KV start phase

  // stage KV tile `tile` into dst (K 8KB + V 8KB)
  auto stageKV = [&](int tile, char* dst) {
    const bf16* k = kS0 + (long)tile * 64 * QKLD;
    const bf16* v = vS0 + tile * 64;
    async_copy16(k, dst);
    async_copy16(k + 32 * QKLD, dst + 4096);
    async_copy16(v, dst + 8192);
    async_copy16(v + 32 * S_, dst + 12288);
  };

  stageKV(tph, ld0);                       // perm(0) -> base 0
  __syncthreads();                         // tile perm(0) landed
  stageKV((tph + 1) & 15, ld0 + 16384);    // perm(1) flies under compute(0)

  f32x16 oA0 = zero16(), oA1 = zero16(), sAccA = zero16();
  f32x16 oB0 = zero16(), oB1 = zero16(), sAccB = zero16();
  const bf16x8 onesF = ones_frag();
  const int rb = (qlo << 7) | fswz(qlo);   // K/V rowbase (row+32 -> +4096)

#pragma unroll 1
  for (int t = 0; t < 16; t++) {
    const int cbase = (t & 1) << 14;
    const int kbase = cbase + rb;
    const int vbase = cbase + 8192 + rb;

    // QK^T swapped, both q-groups share each K fragment
    f32x16 sA0 = zero16(), sA1 = zero16(), sB0 = zero16(), sB1 = zero16();
    __builtin_amdgcn_s_setprio(1);
#pragma unroll
    for (int d4 = 0; d4 < 4; d4++) {
      const int kc2 = d4 * 32 + hi * 16;
      const bf16x8 kf0 = *(const bf16x8*)(lds + (kbase ^ kc2));
      const bf16x8 kf1 = *(const bf16x8*)(lds + ((kbase + 4096) ^ kc2));
      sA0 = __builtin_amdgcn_mfma_f32_32x32x16_bf16(kf0, qA[d4], sA0, 0, 0, 0);
      sA1 = __builtin_amdgcn_mfma_f32_32x32x16_bf16(kf1, qA[d4], sA1, 0, 0, 0);
      sB0 = __builtin_amdgcn_mfma_f32_32x32x16_bf16(kf0, qB[d4], sB0, 0, 0, 0);
      sB1 = __builtin_amdgcn_mfma_f32_32x32x16_bf16(kf1, qB[d4], sB1, 0, 0, 0);
    }

    // PV + row-sum: V fragments read once, used by both groups
#pragma unroll
    for (int ks = 0; ks < 4; ks++) {
      bf16x8 paA, paB;
      if (ks == 0)      { paA = pexp_frag<0>(sA0); paB = pexp_frag<0>(sB0); }
      else if (ks == 1) { paA = pexp_frag<8>(sA0); paB = pexp_frag<8>(sB0); }
      else if (ks == 2) { paA = pexp_frag<0>(sA1); paB = pexp_frag<0>(sB1); }
      else              { paA = pexp_frag<8>(sA1); paB = pexp_frag<8>(sB1); }
      const int off = ks * 32 + hi * 16;
      const bf16x8 v0 = *(const bf16x8*)(lds + (vbase ^ off));
      const bf16x8 v1 = *(const bf16x8*)(lds + ((vbase + 4096) ^ off));
      oA0 = __builtin_amdgcn_mfma_f32_32x32x16_bf16(paA, v0, oA0, 0, 0, 0);
      oA1 = __builtin_amdgcn_mfma_f32_32x32x16_bf16(paA, v1, oA1, 0, 0, 0);
      sAccA = __builtin_amdgcn_mfma_f32_32x32x16_bf16(paA, onesF, sAccA, 0, 0, 0);
      oB0 = __builtin_amdgcn_mfma_f32_32x32x16_bf16(paB, v0, oB0, 0, 0, 0);
      oB1 = __builtin_amdgcn_mfma_f32_32x32x16_bf16(paB, v1, oB1, 0, 0, 0);
      sAccB = __builtin_amdgcn_mfma_f32_32x32x16_bf16(paB, onesF, sAccB, 0, 0, 0);
    }
    __builtin_amdgcn_s_setprio(0);

    __syncthreads();   // all waves done with this buffer; its refill drained at next barrier
    if (t + 2 < 16)    // refill just-computed buffer; loads fly under next tile's compute
      stageKV((tph + t + 2) & 15, ld0 + cbase);
  }

  // epilogue: sums already in C/D layout; O overwrites Q columns
#pragma unroll
  for (int r = 0; r < 16; r++) {
    const int q = (r & 3) + 8 * (r >> 2) + 4 * hi;
    bf16* opA = Qp + (long)(qt * 256 + warp * 32 + q) * QKLD;
    bf16* opB = opA + (long)128 * QKLD;
    const float liA = 1.f / sAccA[r];
    const float liB = 1.f / sAccB[r];
    opA[qlo] = __float2bfloat16(oA0[r] * liA);
    opA[32 + qlo] = __float2bfloat16(oA1[r] * liA);
    opB[qlo] = __float2bfloat16(oB0[r] * liB);
    opB[32 + qlo] = __float2bfloat16(oB1[r] * liB);
  }
}

// ---------- fuse1: xlnB = bf16(LN(x + gather(attn1+attn2))) ----------
__global__ __launch_bounds__(256) void fuse1_kernel(const float* __restrict__ x,
                                                    const float* __restrict__ a1,
                                                    const float* __restrict__ a2,
                                                    const int* __restrict__ idx,
                                                    const int* __restrict__ Np,
                                                    const float* __restrict__ gw,
                                                    const float* __restrict__ bw,
                                                    bf16* __restrict__ xlnB) {
  const int N = *Np;
  const int row = blockIdx.x * 4 + (threadIdx.x >> 6);
  const int lane = threadIdx.x & 63;
  const int b = row >> 10, s = row & 1023;
  const int j = (s < N) ? idx[b * NV_ + s] : s;
  const float* xp = x + (long)row * D_ + lane * 8;
  const float* p1 = a1 + ((long)b * S_ + j) * D_ + lane * 8;
  const float* p2 = a2 + ((long)b * S_ + j) * D_ + lane * 8;
  float v[8];
  float sum = 0.f;
#pragma unroll
  for (int q = 0; q < 2; q++) {
    const float4 t = ((const float4*)xp)[q];
    const float4 u = ((const float4*)p1)[q];
    const float4 w = ((const float4*)p2)[q];
    v[q * 4 + 0] = t.x + u.x + w.x; v[q * 4 + 1] = t.y + u.y + w.y;
    v[q * 4 + 2] = t.z + u.z + w.z; v[q * 4 + 3] = t.w + u.w + w.w;
  }
#pragma unroll
  for (int i = 0; i < 8; i++) sum += v[i];
#pragma unroll
  for (int o = 1; o < 64; o <<= 1) sum += __shfl_xor(sum, o, 64);
  const float mu = sum * (1.f / D_);
  float var = 0.f;
#pragma unroll
  for (int i = 0; i < 8; i++) { const float t = v[i] - mu; var += t * t; }
#pragma unroll
  for (int o = 1; o < 64; o <<= 1) var += __shfl_xor(var, o, 64);
  const float rs = rsqrtf(var * (1.f / D_) + 1e-5f);
#pragma unroll
  for (int i = 0; i < 8; i++) {
    const int d = lane * 8 + i;
    xlnB[(long)row * D_ + d] = __float2bfloat16((v[i] - mu) * rs * gw[d] + bw[d]);
  }
}

// ---------- fuse2: out = LN(xln + y) ----------
__global__ __launch_bounds__(256) void fuse2_kernel(const bf16* __restrict__ xlnB,
                                                    const bf16* __restrict__ ybf,
                                                    const float* __restrict__ gw,
                                                    const float* __restrict__ bw,
                                                    float* __restrict__ out) {
  const int row = blockIdx.x * 4 + (threadIdx.x >> 6);
  const int lane = threadIdx.x & 63;
  const bf16* xp = xlnB + (long)row * D_ + lane * 8;
  const bf16* yp = ybf + (long)row * D_ + lane * 8;
  float v[8];
  float sum = 0.f;
#pragma unroll
  for (int i = 0; i < 8; i++) {
    v[i] = __bfloat162float(xp[i]) + __bfloat162float(yp[i]);
    sum += v[i];
  }
#pragma unroll
  for (int o = 1; o < 64; o <<= 1) sum += __shfl_xor(sum, o, 64);
  const float mu = sum * (1.f / D_);
  float var = 0.f;
#pragma unroll
  for (int i = 0; i < 8; i++) { const float t = v[i] - mu; var += t * t; }
#pragma unroll
  for (int o = 1; o < 64; o <<= 1) var += __shfl_xor(var, o, 64);
  const float rs = rsqrtf(var * (1.f / D_) + 1e-5f);
#pragma unroll
  for (int i = 0; i < 8; i++) {
    const int d = lane * 8 + i;
    out[(long)row * D_ + d] = (v[i] - mu) * rs * gw[d] + bw[d];
  }
}

extern "C" void kernel_launch(void* const* d_in, const int* in_sizes, int n_in,
                              void* d_out, int out_size, void* d_ws, size_t ws_size,
                              hipStream_t stream) {
  const float* x   = (const float*)d_in[0];
  const int* idx1  = (const int*)d_in[1];
  const int* idx2  = (const int*)d_in[2];
  const int* Np    = (const int*)d_in[3];
  const float* b_conv1 = (const float*)d_in[13];
  const float* b_conv2 = (const float*)d_in[15];
  const float* g1    = (const float*)d_in[16];
  const float* beta1 = (const float*)d_in[17];
  const float* g2    = (const float*)d_in[18];
  const float* beta2 = (const float*)d_in[19];

  float* outp  = (float*)d_out;
  float* attn1 = outp + BSD_;

  // workspace layout (72 MB, no live overlaps)
  const size_t DD = (size_t)D_ * D_;
  char* w = (char*)d_ws;
  bf16* wT  = (bf16*)w;                          // [0,4M): q1,k1,v1,q2,k2,v2,o1,o2
  bf16* w1T = wT + 8 * DD;                       // [4,6M): [DF][D]
  bf16* w2T = w1T + (size_t)DF_ * D_;            // [6,8M): [D][DF]
  bf16* qk  = (bf16*)(w + (8ll << 20));          // [8,40M): [8192][2048]; Q cols become O
  bf16* xl1 = (bf16*)(w + (40ll << 20));         // [40,48M)
  bf16* xlnB = (bf16*)(w + (48ll << 20));        // [48,56M)
  bf16* vtb = (bf16*)(w + (56ll << 20));         // [56,72M): V^T (set,b,h)[DH][S]
  bf16* ffn = qk;                                 // reuse (qk dead after Wo)
  bf16* ybf = xl1;                                // reuse

  WP16 wp;
  const float* attnW[8] = {(const float*)d_in[4], (const float*)d_in[5], (const float*)d_in[6],
                           (const float*)d_in[8], (const float*)d_in[9], (const float*)d_in[10],
                           (const float*)d_in[7], (const float*)d_in[11]};
  for (int z = 0; z < 8; z++) {
    wp.p[z].src = attnW[z];
    wp.p[z].dst = wT + (size_t)z * DD;
    wp.p[z].srcLd = D_; wp.p[z].dstLd = D_;
    wp.p[z].scale = (z == 0 || z == 3) ? 0.1803368801f : 1.f;  // 0.125*log2e into Wq
  }
  for (int j = 0; j < 4; j++) {
    wp.p[8 + j].src = (const float*)d_in[12] + 512 * j;
    wp.p[8 + j].dst = w1T + (size_t)(512 * j) * D_;
    wp.p[8 + j].srcLd = DF_; wp.p[8 + j].dstLd = D_;
    wp.p[8 + j].scale = 1.f;
  }
  for (int j = 0; j < 4; j++) {
    wp.p[12 + j].src = (const float*)d_in[14] + (size_t)(512 * j) * D_;
    wp.p[12 + j].dst = w2T + 512 * j;
    wp.p[12 + j].srcLd = D_; wp.p[12 + j].dstLd = DF_;
    wp.p[12 + j].scale = 1.f;
  }

  const dim3 tb(32, 8);
  wtrans16_kernel<<<dim3(16, 16, 16), tb, 0, stream>>>(wp);

  gather_cvt_kernel<<<BS_ / 2, 256, 0, stream>>>(x, idx1, Np, xl1);

  // fused QKV for both sets (logical N=3072): Q/K -> qk (ld 2048), V -> vtb (transposed)
  gemm_bt<128, 128, 4, 4, 0, 0, 0, 1><<<dim3(BS_ / 128, 3072 / 128, 1), 256, 0, stream>>>(
      xl1, D_, 0, wT, 0, nullptr, qk, QKLD, 0, D_, vtb);

  // flash: 512 blocks (2/CU); O in-place over Q columns
  flash_kernel<<<512, 256, 0, stream>>>(qk, vtb);

  // Wo GEMMs batched z=2: A = qk Q-cols (lda 2048, set stride 1024), out fp32
  gemm_bt<128, 128, 4, 4, 1, 0, 0, 0><<<dim3(BS_ / 128, D_ / 128, 2), 256, 0, stream>>>(
      qk, QKLD, 1024, wT + 6 * DD, (long)DD, nullptr, attn1, D_, (long)BSD_, D_, nullptr);

  fuse1_kernel<<<BS_ / 4, 256, 0, stream>>>(x, attn1, attn1 + BSD_, idx2, Np, g1, beta1, xlnB);

  gemm_bt<128, 128, 4, 4, 0, 1, 1, 0><<<dim3(BS_ / 128, DF_ / 128, 1), 256, 0, stream>>>(
      xlnB, D_, 0, w1T, 0, b_conv1, ffn, DF_, 0, D_, nullptr);
  // FFN2: 128x128 (32 MFMA/wave per barrier on the K=2048-deep loop)
  gemm_bt<128, 128, 4, 4, 0, 1, 0, 0><<<dim3(BS_ / 128, D_ / 128, 1), 256, 0, stream>>>(
      ffn, DF_, 0, w2T, 0, b_conv2, ybf, D_, 0, DF_, nullptr);

  fuse2_kernel<<<BS_ / 4, 256, 0, stream>>>(xlnB, ybf, g2, beta2, outp);
}

// Round 17
// 179.930 us; speedup vs baseline: 1.0566x; 1.0566x over previous
//
#include <hip/hip_runtime.h>
#include <hip/hip_bf16.h>
#include <stdint.h>

#define B_ 8
#define S_ 1024
#define NV_ 768
#define D_ 512
#define DF_ 2048
#define H_ 8
#define DH_ 64
#define BS_ (B_*S_)
#define BSD_ ((size_t)B_*S_*D_)
#define QKLD 2048   // qk buffer leading dim: [q1|k1|q2|k2] x 512

typedef __bf16 bf16x8 __attribute__((ext_vector_type(8)));
typedef float f32x4 __attribute__((ext_vector_type(4)));
typedef float f32x16 __attribute__((ext_vector_type(16)));
typedef __hip_bfloat16 bf16;

__device__ __forceinline__ void async_copy16(const void* g, void* l) {
  __builtin_amdgcn_global_load_lds((const __attribute__((address_space(1))) void*)g,
                                   (__attribute__((address_space(3))) void*)l, 16, 0, 0);
}

// ---------------- GEMM swizzle (16-row fragments); NT = threads in block ----
template<int NT>
__device__ __forceinline__ void stage_tile(const bf16* __restrict__ g, int gRow0, long ldg,
                                           int gCol0, bf16* lds, int rows, int tid) {
  const int totalBytes = rows << 7;
  for (int off = tid * 16; off < totalBytes; off += NT * 16) {
    const int r = off >> 7;
    const int c = off & 127;
    const int srcByte = c ^ ((r & 7) << 4);
    const bf16* gp = g + (long)(gRow0 + r) * ldg + gCol0 + (srcByte >> 1);
    async_copy16(gp, (char*)lds + off);
  }
}
__device__ __forceinline__ bf16x8 lds_frag(const bf16* base, int row, int kElem) {
  const int byte = (row << 7) + ((kElem << 1) ^ ((row & 7) << 4));
  return *(const bf16x8*)((const char*)base + byte);
}

// ---------------- flash swizzle (32-row fragments, stride-8 read phases) -----
__device__ __forceinline__ int fswz(int row) {
  return ((((row >> 3) & 3) << 1) | (row & 1)) << 4;
}

// Fast 2^s -> bf16 fragment, Schraudolph: bits=(int)(2^23*s + bias).
// No max subtraction: |s| <= ~24 by Cauchy-Schwarz on q,k norms; valid (-126,30).
#define SCH_BIAS 1064872540.f
template<int BASE>
__device__ __forceinline__ bf16x8 pexp_frag(const f32x16& s) {
  union { unsigned u[4]; bf16x8 b; } r;
#pragma unroll
  for (int e = 0; e < 4; e++) {
    const int i0 = (int)fmaf(s[BASE + 2 * e], 8388608.f, SCH_BIAS);
    const int i1 = (int)fmaf(s[BASE + 2 * e + 1], 8388608.f, SCH_BIAS);
    r.u[e] = __builtin_amdgcn_perm((unsigned)i1, (unsigned)i0, 0x07060302u);
  }
  return r.b;
}

__device__ __forceinline__ bf16x8 ones_frag() {
  union { ushort u[8]; bf16x8 b; } r;
#pragma unroll
  for (int e = 0; e < 8; e++) r.u[e] = 0x3F80;  // bf16 1.0
  return r.b;
}

__device__ __forceinline__ f32x16 zero16() {
  f32x16 z;
#pragma unroll
  for (int i = 0; i < 16; i++) z[i] = 0.f;
  return z;
}

// ---------- merged 16-panel weight transpose+convert ----------
struct WPanel { const float* src; bf16* dst; int srcLd, dstLd; float scale; };
struct WP16 { WPanel p[16]; };
__global__ __launch_bounds__(256) void wtrans16_kernel(WP16 ws) {
  __shared__ float tile[32][33];
  const WPanel pa = ws.p[blockIdx.z];
  const int tx = threadIdx.x, ty = threadIdx.y;
  const int n0 = blockIdx.x * 32, k0 = blockIdx.y * 32;
#pragma unroll
  for (int i = 0; i < 4; i++)
    tile[ty + i * 8][tx] = pa.src[(long)(k0 + ty + i * 8) * pa.srcLd + n0 + tx];
  __syncthreads();
#pragma unroll
  for (int i = 0; i < 4; i++)
    pa.dst[(long)(n0 + ty + i * 8) * pa.dstLd + k0 + tx] =
        __float2bfloat16(tile[tx][ty + i * 8] * pa.scale);
}

// ---------- gather + fp32->bf16 ----------
__global__ __launch_bounds__(256) void gather_cvt_kernel(const float* __restrict__ x,
                                                         const int* __restrict__ idx,
                                                         const int* __restrict__ Np,
                                                         bf16* __restrict__ out) {
  const int N = *Np;
  const int row = blockIdx.x * 2 + (threadIdx.x >> 7);
  const int t = threadIdx.x & 127;
  const int b = row >> 10, s = row & 1023;
  const int src = (s < N) ? idx[b * NV_ + s] : s;
  const float4 v = *(const float4*)(x + ((long)b * S_ + src) * D_ + t * 4);
  ushort4 u;
  u.x = (ushort)__bfloat16_as_ushort(__float2bfloat16(v.x));
  u.y = (ushort)__bfloat16_as_ushort(__float2bfloat16(v.y));
  u.z = (ushort)__bfloat16_as_ushort(__float2bfloat16(v.z));
  u.w = (ushort)__bfloat16_as_ushort(__float2bfloat16(v.w));
  *(ushort4*)(out + (long)row * D_ + t * 4) = u;
}

// ---------- GEMM (R15 proven: 2-barrier + XCD swizzle + K-stagger) -----------
// K-phase stagger: block starts its K loop at phase (l & (nk-1)) and wraps —
// accumulation commutative; desyncs the stage-burst convoy across blocks.
// QKV mode: logical N=3072 (two sets of [Q|K|V]); Q/K cols -> qk[row][set*1024+c1]
// (ld 2048); V cols -> vtb (B,H,DH,S layout, key bits 2<->3 permuted).
template<int BM, int BN, int MR, int NR, int OUTF, int BIAS, int RELU, int QKV>
__global__ __launch_bounds__(BM / (MR * 16) * (BN / (NR * 16)) * 64, 4)
void gemm_bt(const bf16* __restrict__ A, long lda, long sAz,
             const bf16* __restrict__ Bt, long sBz,
             const float* __restrict__ bias,
             void* __restrict__ C, long ldc, long sCz,
             int K, bf16* __restrict__ vtbOut) {
  constexpr int WC = BN / (NR * 16);
  constexpr int WR = BM / (MR * 16);
  constexpr int NT = WR * WC * 64;
  __shared__ bf16 As[BM * 64];
  __shared__ bf16 Bs[BN * 64];
  const int tid = threadIdx.x;
  const int lane = tid & 63, wave = tid >> 6;
  const int wr = wave / WC, wc = wave % WC;
  const int g = lane >> 4, lr = lane & 15;

  // XCD-chunked swizzle (bijective; gridDim.x%8==0 for all our grids)
  const int nx = gridDim.x;
  const int ch = nx >> 3;
  const int l = blockIdx.x + nx * blockIdx.y;
  const int xcd = l & 7, i = l >> 3;
  const int bx = xcd * ch + i % ch;
  const int by = i / ch;
  const int m0 = bx * BM, n0 = by * BN;
  const int z = blockIdx.z;
  A += (long)z * sAz;
  Bt += (long)z * sBz;

  f32x4 acc[MR][NR];
#pragma unroll
  for (int m = 0; m < MR; m++)
#pragma unroll
    for (int n = 0; n < NR; n++) acc[m][n] = (f32x4){0.f, 0.f, 0.f, 0.f};

  const int nk = K >> 6;                 // power of 2 for all our shapes
  const int ph = l & (nk - 1);           // per-block K start phase
#pragma unroll 1
  for (int s = 0; s < nk; s++) {
    const int kt = ((s + ph) & (nk - 1)) << 6;
    stage_tile<NT>(A, m0, lda, kt, As, BM, tid);
    stage_tile<NT>(Bt, n0, K, kt, Bs, BN, tid);
    __syncthreads();
#pragma unroll
    for (int ks = 0; ks < 64; ks += 32) {
      const int kk = ks + g * 8;
      bf16x8 aF[MR], bF[NR];
#pragma unroll
      for (int m = 0; m < MR; m++) aF[m] = lds_frag(As, wr * (MR * 16) + m * 16 + lr, kk);
#pragma unroll
      for (int n = 0; n < NR; n++) bF[n] = lds_frag(Bs, wc * (NR * 16) + n * 16 + lr, kk);
#pragma unroll
      for (int m = 0; m < MR; m++)
#pragma unroll
        for (int n = 0; n < NR; n++)
          acc[m][n] = __builtin_amdgcn_mfma_f32_16x16x32_bf16(aF[m], bF[n], acc[m][n], 0, 0, 0);
    }
    __syncthreads();
  }

#pragma unroll
  for (int m = 0; m < MR; m++) {
#pragma unroll
    for (int n = 0; n < NR; n++) {
      const int row = m0 + wr * (MR * 16) + m * 16 + g * 4;
      const int col = n0 + wc * (NR * 16) + n * 16 + lr;
      if (QKV) {
        const int set = (col >= 1536) ? 1 : 0;
        const int c1 = col - set * 1536;
        if (c1 < 1024) {           // Q or K column -> qk buffer (block-uniform)
          bf16* cp = (bf16*)C + (long)row * QKLD + set * 1024 + c1;
#pragma unroll
          for (int r = 0; r < 4; r++) cp[(long)r * QKLD] = __float2bfloat16(acc[m][n][r]);
        } else {                   // V column -> vtb transposed + key-permuted
          const int d = c1 - 1024;                       // 0..511
          const int zz = set * 64 + ((row >> 10) << 3) + (d >> 6);
          const int s2 = row & 1023;                     // bits 0-1 zero; bits 2-3 const
          const int sp = (s2 & ~12) | ((s2 & 4) << 1) | ((s2 & 8) >> 1);
          ushort4 pk;
          pk.x = (ushort)__bfloat16_as_ushort(__float2bfloat16(acc[m][n][0]));
          pk.y = (ushort)__bfloat16_as_ushort(__float2bfloat16(acc[m][n][1]));
          pk.z = (ushort)__bfloat16_as_ushort(__float2bfloat16(acc[m][n][2]));
          pk.w = (ushort)__bfloat16_as_ushort(__float2bfloat16(acc[m][n][3]));
          *(ushort4*)(vtbOut + (((long)(zz * 64 + (d & 63))) << 10) + sp) = pk;
        }
      } else {
        const float bv = BIAS ? bias[col] : 0.f;
#pragma unroll
        for (int r = 0; r < 4; r++) {
          float v = acc[m][n][r] + bv;
          if (RELU) v = fmaxf(v, 0.f);
          if (OUTF) ((float*)C)[(long)z * sCz + (long)(row + r) * ldc + col] = v;
          else ((bf16*)C)[(long)z * sCz + (long)(row + r) * ldc + col] = __float2bfloat16(v);
        }
      }
    }
  }
}

// ---------- flash attention (R11/R15 proven): swapped-QK 32x32, 256 q-rows ----
// 2 q-groups double the compute window per KV tile and halve K/V traffic.
// Q fills 32KB LDS, hoisted to regs; LDS becomes 2x16KB KV rotate-buffer.
// Sequential KV order (same-sbh blocks share each tile in L2 — R16 showed
// staggering destroys that broadcast locality and regresses).
__global__ __launch_bounds__(256, 2) void flash_kernel(bf16* __restrict__ qk,
                                                       const bf16* __restrict__ vtb) {
  __shared__ char lds[32768];
  const int tid = threadIdx.x;
  const int lane = tid & 63, warp = tid >> 6;
  const int qlo = lane & 31, hi = lane >> 5;

  // bijective XCD swizzle: each XCD gets 64 consecutive swz ids (16 sbh units)
  const int bid = (int)blockIdx.x;
  const int swz = (bid & 7) * 64 + (bid >> 3);
  const int qt = swz & 3;                 // 4 q-tiles of 256 rows
  const int sbh = swz >> 2;               // set*64 + b*8 + h
  const int set = sbh >> 6;
  const int b = (sbh >> 3) & 7, h = sbh & 7;

  bf16* Qp = qk + (long)b * S_ * QKLD + set * 1024 + h * DH_;
  const bf16* Kp = Qp + 512;
  const bf16* Vp = vtb + (long)sbh * DH_ * S_;

  // staging geometry (tile-invariant): thread covers row r0 (+32k) per 4KB chunk
  const int r0 = tid >> 3;
  const int cbyt = (tid & 7) << 4;
  const int sb = cbyt ^ fswz(r0);         // fswz(r0+32k) == fswz(r0)
  char* const ld0 = lds + tid * 16;       // wave-linear LDS dest

  // Q: 256 rows fill all 32KB (chunk i holds rows i*32 + r0)
  {
    const bf16* qS = Qp + (long)(qt * 256 + r0) * QKLD + (sb >> 1);
#pragma unroll
    for (int i = 0; i < 8; i++) async_copy16(qS + (long)i * 32 * QKLD, ld0 + i * 4096);
  }
  __syncthreads();

  // hoist Q frags; global row R lives at byte (R<<7)|fswz(R) (since 32*128=4096)
  const int qrow = warp * 32 + qlo;
  const int qrb = (qrow << 7) | fswz(qrow);
  bf16x8 qA[4], qB[4];
#pragma unroll
  for (int d4 = 0; d4 < 4; d4++) {
    const int kc2 = d4 * 32 + hi * 16;
    qA[d4] = *(const bf16x8*)(lds + (qrb ^ kc2));
    qB[d4] = *(const bf16x8*)(lds + ((qrb + 16384) ^ kc2));
  }
  __syncthreads();   // Q consumed; whole LDS free for KV buffers

  const bf16* kS = Kp + (long)r0 * QKLD + (sb >> 1);
  const bf16* vS = Vp + (long)r0 * S_ + (sb >> 1);
  // KV tile0 -> base 0
  async_copy16(kS, ld0);
  async_copy16(kS + 32 * QKLD, ld0 + 4096);
  async_copy16(vS, ld0 + 8192);
  async_copy16(vS + 32 * S_, ld0 + 12288);
  __syncthreads();   // tile0 landed
  // KV tile1 -> base 16384 (flies under tile0 compute)
  kS += 64 * QKLD; vS += 64;
  async_copy16(kS, ld0 + 16384);
  async_copy16(kS + 32 * QKLD, ld0 + 16384 + 4096);
  async_copy16(vS, ld0 + 16384 + 8192);
  async_copy16(vS + 32 * S_, ld0 + 16384 + 12288);

  f32x16 oA0 = zero16(), oA1 = zero16(), sAccA = zero16();
  f32x16 oB0 = zero16(), oB1 = zero16(), sAccB = zero16();
  const bf16x8 onesF = ones_frag();
  const int rb = (qlo << 7) | fswz(qlo);   // K/V rowbase (row+32 -> +4096)

#pragma unroll 1
  for (int t = 0; t < 16; t++) {
    const int cbase = (t & 1) << 14;
    const int kbase = cbase + rb;
    const int vbase = cbase + 8192 + rb;

    // QK^T swapped, both q-groups share each K fragment
    f32x16 sA0 = zero16(), sA1 = zero16(), sB0 = zero16(), sB1 = zero16();
    __builtin_amdgcn_s_setprio(1);
#pragma unroll
    for (int d4 = 0; d4 < 4; d4++) {
      const int kc2 = d4 * 32 + hi * 16;
      const bf16x8 kf0 = *(const bf16x8*)(lds + (kbase ^ kc2));
      const bf16x8 kf1 = *(const bf16x8*)(lds + ((kbase + 4096) ^ kc2));
      sA0 = __builtin_amdgcn_mfma_f32_32x32x16_bf16(kf0, qA[d4], sA0, 0, 0, 0);
      sA1 = __builtin_amdgcn_mfma_f32_32x32x16_bf16(kf1, qA[d4], sA1, 0, 0, 0);
      sB0 = __builtin_amdgcn_mfma_f32_32x32x16_bf16(kf0, qB[d4], sB0, 0, 0, 0);
      sB1 = __builtin_amdgcn_mfma_f32_32x32x16_bf16(kf1, qB[d4], sB1, 0, 0, 0);
    }

    // PV + row-sum: V fragments read once, used by both groups
#pragma unroll
    for (int ks = 0; ks < 4; ks++) {
      bf16x8 paA, paB;
      if (ks == 0)      { paA = pexp_frag<0>(sA0); paB = pexp_frag<0>(sB0); }
      else if (ks == 1) { paA = pexp_frag<8>(sA0); paB = pexp_frag<8>(sB0); }
      else if (ks == 2) { paA = pexp_frag<0>(sA1); paB = pexp_frag<0>(sB1); }
      else              { paA = pexp_frag<8>(sA1); paB = pexp_frag<8>(sB1); }
      const int off = ks * 32 + hi * 16;
      const bf16x8 v0 = *(const bf16x8*)(lds + (vbase ^ off));
      const bf16x8 v1 = *(const bf16x8*)(lds + ((vbase + 4096) ^ off));
      oA0 = __builtin_amdgcn_mfma_f32_32x32x16_bf16(paA, v0, oA0, 0, 0, 0);
      oA1 = __builtin_amdgcn_mfma_f32_32x32x16_bf16(paA, v1, oA1, 0, 0, 0);
      sAccA = __builtin_amdgcn_mfma_f32_32x32x16_bf16(paA, onesF, sAccA, 0, 0, 0);
      oB0 = __builtin_amdgcn_mfma_f32_32x32x16_bf16(paB, v0, oB0, 0, 0, 0);
      oB1 = __builtin_amdgcn_mfma_f32_32x32x16_bf16(paB, v1, oB1, 0, 0, 0);
      sAccB = __builtin_amdgcn_mfma_f32_32x32x16_bf16(paB, onesF, sAccB, 0, 0, 0);
    }
    __builtin_amdgcn_s_setprio(0);

    __syncthreads();   // all waves done with this buffer; its refill drained at next barrier
    if (t + 2 < 16) {  // refill just-computed buffer; loads fly under next tile's compute
      kS += 64 * QKLD; vS += 64;
      char* dst = ld0 + cbase;
      async_copy16(kS, dst);
      async_copy16(kS + 32 * QKLD, dst + 4096);
      async_copy16(vS, dst + 8192);
      async_copy16(vS + 32 * S_, dst + 12288);
    }
  }

  // epilogue: sums already in C/D layout; O overwrites Q columns
#pragma unroll
  for (int r = 0; r < 16; r++) {
    const int q = (r & 3) + 8 * (r >> 2) + 4 * hi;
    bf16* opA = Qp + (long)(qt * 256 + warp * 32 + q) * QKLD;
    bf16* opB = opA + (long)128 * QKLD;
    const float liA = 1.f / sAccA[r];
    const float liB = 1.f / sAccB[r];
    opA[qlo] = __float2bfloat16(oA0[r] * liA);
    opA[32 + qlo] = __float2bfloat16(oA1[r] * liA);
    opB[qlo] = __float2bfloat16(oB0[r] * liB);
    opB[32 + qlo] = __float2bfloat16(oB1[r] * liB);
  }
}

// ---------- fuse1: xlnB = bf16(LN(x + gather(attn1+attn2))) ----------
__global__ __launch_bounds__(256) void fuse1_kernel(const float* __restrict__ x,
                                                    const float* __restrict__ a1,
                                                    const float* __restrict__ a2,
                                                    const int* __restrict__ idx,
                                                    const int* __restrict__ Np,
                                                    const float* __restrict__ gw,
                                                    const float* __restrict__ bw,
                                                    bf16* __restrict__ xlnB) {
  const int N = *Np;
  const int row = blockIdx.x * 4 + (threadIdx.x >> 6);
  const int lane = threadIdx.x & 63;
  const int b = row >> 10, s = row & 1023;
  const int j = (s < N) ? idx[b * NV_ + s] : s;
  const float* xp = x + (long)row * D_ + lane * 8;
  const float* p1 = a1 + ((long)b * S_ + j) * D_ + lane * 8;
  const float* p2 = a2 + ((long)b * S_ + j) * D_ + lane * 8;
  float v[8];
  float sum = 0.f;
#pragma unroll
  for (int q = 0; q < 2; q++) {
    const float4 t = ((const float4*)xp)[q];
    const float4 u = ((const float4*)p1)[q];
    const float4 w = ((const float4*)p2)[q];
    v[q * 4 + 0] = t.x + u.x + w.x; v[q * 4 + 1] = t.y + u.y + w.y;
    v[q * 4 + 2] = t.z + u.z + w.z; v[q * 4 + 3] = t.w + u.w + w.w;
  }
#pragma unroll
  for (int i = 0; i < 8; i++) sum += v[i];
#pragma unroll
  for (int o = 1; o < 64; o <<= 1) sum += __shfl_xor(sum, o, 64);
  const float mu = sum * (1.f / D_);
  float var = 0.f;
#pragma unroll
  for (int i = 0; i < 8; i++) { const float t = v[i] - mu; var += t * t; }
#pragma unroll
  for (int o = 1; o < 64; o <<= 1) var += __shfl_xor(var, o, 64);
  const float rs = rsqrtf(var * (1.f / D_) + 1e-5f);
#pragma unroll
  for (int i = 0; i < 8; i++) {
    const int d = lane * 8 + i;
    xlnB[(long)row * D_ + d] = __float2bfloat16((v[i] - mu) * rs * gw[d] + bw[d]);
  }
}

// ---------- fuse2: out = LN(xln + y) ----------
__global__ __launch_bounds__(256) void fuse2_kernel(const bf16* __restrict__ xlnB,
                                                    const bf16* __restrict__ ybf,
                                                    const float* __restrict__ gw,
                                                    const float* __restrict__ bw,
                                                    float* __restrict__ out) {
  const int row = blockIdx.x * 4 + (threadIdx.x >> 6);
  const int lane = threadIdx.x & 63;
  const bf16* xp = xlnB + (long)row * D_ + lane * 8;
  const bf16* yp = ybf + (long)row * D_ + lane * 8;
  float v[8];
  float sum = 0.f;
#pragma unroll
  for (int i = 0; i < 8; i++) {
    v[i] = __bfloat162float(xp[i]) + __bfloat162float(yp[i]);
    sum += v[i];
  }
#pragma unroll
  for (int o = 1; o < 64; o <<= 1) sum += __shfl_xor(sum, o, 64);
  const float mu = sum * (1.f / D_);
  float var = 0.f;
#pragma unroll
  for (int i = 0; i < 8; i++) { const float t = v[i] - mu; var += t * t; }
#pragma unroll
  for (int o = 1; o < 64; o <<= 1) var += __shfl_xor(var, o, 64);
  const float rs = rsqrtf(var * (1.f / D_) + 1e-5f);
#pragma unroll
  for (int i = 0; i < 8; i++) {
    const int d = lane * 8 + i;
    out[(long)row * D_ + d] = (v[i] - mu) * rs * gw[d] + bw[d];
  }
}

extern "C" void kernel_launch(void* const* d_in, const int* in_sizes, int n_in,
                              void* d_out, int out_size, void* d_ws, size_t ws_size,
                              hipStream_t stream) {
  const float* x   = (const float*)d_in[0];
  const int* idx1  = (const int*)d_in[1];
  const int* idx2  = (const int*)d_in[2];
  const int* Np    = (const int*)d_in[3];
  const float* b_conv1 = (const float*)d_in[13];
  const float* b_conv2 = (const float*)d_in[15];
  const float* g1    = (const float*)d_in[16];
  const float* beta1 = (const float*)d_in[17];
  const float* g2    = (const float*)d_in[18];
  const float* beta2 = (const float*)d_in[19];

  float* outp  = (float*)d_out;
  float* attn1 = outp + BSD_;

  // workspace layout (72 MB, no live overlaps)
  const size_t DD = (size_t)D_ * D_;
  char* w = (char*)d_ws;
  bf16* wT  = (bf16*)w;                          // [0,4M): q1,k1,v1,q2,k2,v2,o1,o2
  bf16* w1T = wT + 8 * DD;                       // [4,6M): [DF][D]
  bf16* w2T = w1T + (size_t)DF_ * D_;            // [6,8M): [D][DF]
  bf16* qk  = (bf16*)(w + (8ll << 20));          // [8,40M): [8192][2048]; Q cols become O
  bf16* xl1 = (bf16*)(w + (40ll << 20));         // [40,48M)
  bf16* xlnB = (bf16*)(w + (48ll << 20));        // [48,56M)
  bf16* vtb = (bf16*)(w + (56ll << 20));         // [56,72M): V^T (set,b,h)[DH][S]
  bf16* ffn = qk;                                 // reuse (qk dead after Wo)
  bf16* ybf = xl1;                                // reuse

  WP16 wp;
  const float* attnW[8] = {(const float*)d_in[4], (const float*)d_in[5], (const float*)d_in[6],
                           (const float*)d_in[8], (const float*)d_in[9], (const float*)d_in[10],
                           (const float*)d_in[7], (const float*)d_in[11]};
  for (int z = 0; z < 8; z++) {
    wp.p[z].src = attnW[z];
    wp.p[z].dst = wT + (size_t)z * DD;
    wp.p[z].srcLd = D_; wp.p[z].dstLd = D_;
    wp.p[z].scale = (z == 0 || z == 3) ? 0.1803368801f : 1.f;  // 0.125*log2e into Wq
  }
  for (int j = 0; j < 4; j++) {
    wp.p[8 + j].src = (const float*)d_in[12] + 512 * j;
    wp.p[8 + j].dst = w1T + (size_t)(512 * j) * D_;
    wp.p[8 + j].srcLd = DF_; wp.p[8 + j].dstLd = D_;
    wp.p[8 + j].scale = 1.f;
  }
  for (int j = 0; j < 4; j++) {
    wp.p[12 + j].src = (const float*)d_in[14] + (size_t)(512 * j) * D_;
    wp.p[12 + j].dst = w2T + 512 * j;
    wp.p[12 + j].srcLd = D_; wp.p[12 + j].dstLd = DF_;
    wp.p[12 + j].scale = 1.f;
  }

  const dim3 tb(32, 8);
  wtrans16_kernel<<<dim3(16, 16, 16), tb, 0, stream>>>(wp);

  gather_cvt_kernel<<<BS_ / 2, 256, 0, stream>>>(x, idx1, Np, xl1);

  // fused QKV for both sets (logical N=3072): Q/K -> qk (ld 2048), V -> vtb (transposed)
  gemm_bt<128, 128, 4, 4, 0, 0, 0, 1><<<dim3(BS_ / 128, 3072 / 128, 1), 256, 0, stream>>>(
      xl1, D_, 0, wT, 0, nullptr, qk, QKLD, 0, D_, vtb);

  // flash: 512 blocks (2/CU); O in-place over Q columns
  flash_kernel<<<512, 256, 0, stream>>>(qk, vtb);

  // Wo GEMMs batched z=2: A = qk Q-cols (lda 2048, set stride 1024), out fp32
  gemm_bt<128, 128, 4, 4, 1, 0, 0, 0><<<dim3(BS_ / 128, D_ / 128, 2), 256, 0, stream>>>(
      qk, QKLD, 1024, wT + 6 * DD, (long)DD, nullptr, attn1, D_, (long)BSD_, D_, nullptr);

  fuse1_kernel<<<BS_ / 4, 256, 0, stream>>>(x, attn1, attn1 + BSD_, idx2, Np, g1, beta1, xlnB);

  gemm_bt<128, 128, 4, 4, 0, 1, 1, 0><<<dim3(BS_ / 128, DF_ / 128, 1), 256, 0, stream>>>(
      xlnB, D_, 0, w1T, 0, b_conv1, ffn, DF_, 0, D_, nullptr);
  gemm_bt<128, 64, 4, 2, 0, 1, 0, 0><<<dim3(BS_ / 128, D_ / 64, 1), 256, 0, stream>>>(
      ffn, DF_, 0, w2T, 0, b_conv2, ybf, D_, 0, DF_, nullptr);

  fuse2_kernel<<<BS_ / 4, 256, 0, stream>>>(xlnB, ybf, g2, beta2, outp);
}